// Round 6
// baseline (152.062 us; speedup 1.0000x reference)
//
#include <hip/hip_runtime.h>
#include <hip/hip_bf16.h>
#include <cstdint>

// LSTM cell, B=16384, IN=512, H=512, fused 4-gate bf16 MFMA GEMM.
// Round 6: DIAGNOSTIC. Real kernel = round-5 (unchanged, validated).
// Added probe_nostage: round-5 K-loop minus staging/vmcnt/epilogue-I/O,
// to bisect core-loop-bound (H1) vs staging-bound (H2). Probe output goes
// to d_ws (junk, rewritten by prepasses every replay -> deterministic).

typedef __attribute__((ext_vector_type(8))) __bf16 bf16x8;
typedef __attribute__((ext_vector_type(4))) float f32x4;
typedef __attribute__((address_space(3))) char lds_char;

#define GLOAD_LDS16(gp, lp)                                                        \
    __builtin_amdgcn_global_load_lds(                                              \
        (const __attribute__((address_space(1))) void*)(gp),                       \
        (__attribute__((address_space(3))) void*)(lp), 16, 0, 0)

#define BAR()  asm volatile("s_barrier" ::: "memory")
#define VMW8() asm volatile("s_waitcnt vmcnt(8)" ::: "memory")
#define VMW4() asm volatile("s_waitcnt vmcnt(4)" ::: "memory")
#define VMW0() asm volatile("s_waitcnt vmcnt(0)" ::: "memory")
#define LGK0() { asm volatile("s_waitcnt lgkmcnt(0)" ::: "memory");                \
                 __builtin_amdgcn_sched_barrier(0); }
#define DSR(dst, off)                                                              \
    asm volatile("ds_read_b128 %0, %1" : "=v"(dst) : "v"(lds3 + (off)))

__device__ __forceinline__ unsigned short f2bf(float f) {
    unsigned int u = __float_as_uint(f);
    u = (u + 0x7FFFu + ((u >> 16) & 1u)) >> 16;   // RNE
    return (unsigned short)u;
}
__device__ __forceinline__ float tanh_fast(float x) {
    float ax = fabsf(x);
    float e  = __expf(2.f * ax);
    float t  = 1.f - 2.f / (e + 1.f);
    return copysignf(t, x);
}

// ---------------- prepass A (unchanged, verified) ----------------
__global__ __launch_bounds__(256) void conv_a_kernel(const float* __restrict__ x,
                                                     const float* __restrict__ h,
                                                     unsigned short* __restrict__ A) {
    int G  = blockIdx.x * 256 + threadIdx.x;
    int b  = G >> 10;
    int p  = G & 1023;
    int mt = b >> 5;
    int kt = (b >> 1) & 15;
    int ks = b & 1;
    int row = p >> 2;
    int c   = (p & 3) ^ ((row >> 1) & 3);
    int r   = mt * 256 + row;
    int k0  = kt * 64 + ks * 32 + c * 8;
    const float* src = (k0 < 512) ? (x + (size_t)r * 512 + k0)
                                  : (h + (size_t)r * 512 + (k0 - 512));
    const float4* s4 = reinterpret_cast<const float4*>(src);
    float4 v0 = s4[0];
    float4 v1 = s4[1];
    uint4 o;
    o.x = (unsigned)f2bf(v0.x) | ((unsigned)f2bf(v0.y) << 16);
    o.y = (unsigned)f2bf(v0.z) | ((unsigned)f2bf(v0.w) << 16);
    o.z = (unsigned)f2bf(v1.x) | ((unsigned)f2bf(v1.y) << 16);
    o.w = (unsigned)f2bf(v1.z) | ((unsigned)f2bf(v1.w) << 16);
    *reinterpret_cast<uint4*>(A + ((size_t)b * 1024 + p) * 8) = o;
}

// ---------------- prepass B (unchanged, verified) ----------------
__global__ __launch_bounds__(256) void conv_w_kernel(const float* __restrict__ w0,
                                                     const float* __restrict__ w1,
                                                     const float* __restrict__ w2,
                                                     const float* __restrict__ w3,
                                                     unsigned short* __restrict__ Wt) {
    int G  = blockIdx.x * 256 + threadIdx.x;
    int b  = G >> 10;
    int p  = G & 1023;
    int nb = b >> 5;
    int kt = (b >> 1) & 15;
    int ks = b & 1;
    int col = p >> 2;
    int c   = (p & 3) ^ ((col >> 1) & 3);
    int g   = col >> 6;
    int hh  = col & 63;
    int n   = nb * 64 + hh;
    int k0  = kt * 64 + ks * 32 + c * 8;
    const float* Wg = (g == 0) ? w0 : (g == 1) ? w1 : (g == 2) ? w2 : w3;
    unsigned short us[8];
    #pragma unroll
    for (int u = 0; u < 8; ++u) us[u] = f2bf(Wg[(size_t)(k0 + u) * 512 + n]);
    uint4 o;
    o.x = (unsigned)us[0] | ((unsigned)us[1] << 16);
    o.y = (unsigned)us[2] | ((unsigned)us[3] << 16);
    o.z = (unsigned)us[4] | ((unsigned)us[5] << 16);
    o.w = (unsigned)us[6] | ((unsigned)us[7] << 16);
    *reinterpret_cast<uint4*>(Wt + ((size_t)b * 1024 + p) * 8) = o;
}

// ---------------- fused GEMM (round-5, unchanged) ----------------
__global__ __launch_bounds__(512, 2) void lstm_gemm8(
    const char* __restrict__ Apre, const char* __restrict__ Bpre,
    const float* __restrict__ c_cur,
    const float* __restrict__ bi_p, const float* __restrict__ bf_p,
    const float* __restrict__ bo_p, const float* __restrict__ bc_p,
    float* __restrict__ h_out, float* __restrict__ c_out)
{
    extern __shared__ char smem[];
    lds_char* lds3 = (lds_char*)smem;
    const int tid  = threadIdx.x;
    const int lane = tid & 63;
    const int wid  = tid >> 6;
    const int wm   = wid >> 2;
    const int wn   = wid & 3;

    const int nb = blockIdx.x & 7;
    const int mt = blockIdx.x >> 3;

    const int ar    = lane & 15;
    const int swz   = ((lane >> 4) ^ ((ar >> 1) & 3)) << 4;
    const int aoffb = ar * 64 + swz;
    const int boffb = (wn * 16 + ar) * 64 + swz;
    const int swl   = wid * 1024;

    const char* ApreB = Apre + (((size_t)mt * 32) << 14) + (size_t)tid * 16;
    const char* BpreB = Bpre + (((size_t)nb * 32) << 14) + (size_t)tid * 16;

#define STAGE(t, bb) {                                                  \
        const char* ga_ = ApreB + (((size_t)(t)) << 14);                \
        const char* gb_ = BpreB + (((size_t)(t)) << 14);                \
        GLOAD_LDS16(ga_,        smem + (bb) + swl);                     \
        GLOAD_LDS16(ga_ + 8192, smem + (bb) + 8192 + swl);              \
        GLOAD_LDS16(gb_,        smem + (bb) + 16384 + swl);             \
        GLOAD_LDS16(gb_ + 8192, smem + (bb) + 16384 + 8192 + swl); }

    f32x4 acc[4][8];
    #pragma unroll
    for (int g = 0; g < 4; ++g)
        #pragma unroll
        for (int m = 0; m < 8; ++m)
            acc[g][m] = (f32x4){0.f, 0.f, 0.f, 0.f};

    bf16x8 aFr[8], bFr[4];

    STAGE(0, 0);
    STAGE(1, 32768);
    STAGE(2, 65536);

    #pragma unroll 1
    for (int j = 0; j < 32; ++j) {
        const int buf  = (j & 3) << 15;
        const int bufN = ((j + 3) & 3) << 15;

        if (j < 30)      { VMW8(); }
        else if (j == 30){ VMW4(); }
        else             { VMW0(); }
        BAR();

        if (j < 29) STAGE(j + 3, bufN);

        #pragma unroll
        for (int mh = 0; mh < 2; ++mh)
            #pragma unroll
            for (int mi = 0; mi < 4; ++mi)
                DSR(aFr[mh * 4 + mi],
                    buf + wm * 8192 + mh * 4096 + mi * 1024 + aoffb);
        #pragma unroll
        for (int g = 0; g < 4; ++g)
            DSR(bFr[g], buf + 16384 + g * 4096 + boffb);

        LGK0();
        __builtin_amdgcn_s_setprio(1);
        #pragma unroll
        for (int g = 0; g < 4; ++g)
            #pragma unroll
            for (int m = 0; m < 8; ++m)
                acc[g][m] = __builtin_amdgcn_mfma_f32_16x16x32_bf16(
                    aFr[m], bFr[g], acc[g][m], 0, 0, 0);
        __builtin_amdgcn_s_setprio(0);
    }

    const int r4   = (lane >> 4) * 4;
    const int hcol = nb * 64 + wn * 16 + ar;
    const float bii = bi_p[hcol], bff = bf_p[hcol];
    const float boo = bo_p[hcol], bcc = bc_p[hcol];
    #pragma unroll
    for (int m = 0; m < 8; ++m) {
        const int rowb = mt * 256 + wm * 128 + m * 16 + r4;
        #pragma unroll
        for (int rr = 0; rr < 4; ++rr) {
            const size_t o = (size_t)(rowb + rr) * 512 + hcol;
            float gi = acc[0][m][rr] + bii;
            float gf = acc[1][m][rr] + bff;
            float go = acc[2][m][rr] + boo;
            float gc = acc[3][m][rr] + bcc;
            float is = 1.f / (1.f + __expf(-gi));
            float fs = 1.f / (1.f + __expf(-gf));
            float os = 1.f / (1.f + __expf(-go));
            float ct = tanh_fast(gc);
            float cn = fs * c_cur[o] + is * ct;
            h_out[o] = os * tanh_fast(cn);
            c_out[o] = cn;
        }
    }
#undef STAGE
}

// ---------------- PROBE: K-loop minus staging/vmcnt/epilogue-I/O ----------------
// Identical grid/block/LDS/occupancy and identical per-iteration ds_read+MFMA
// structure to lstm_gemm8; no global_load_lds, no vmcnt waits. Reads junk LDS
// (data-independent MFMA timing), stores 1 float/thread to scratch.
__global__ __launch_bounds__(512, 2) void probe_nostage(float* __restrict__ out)
{
    extern __shared__ char smem[];
    lds_char* lds3 = (lds_char*)smem;
    const int tid  = threadIdx.x;
    const int lane = tid & 63;
    const int wid  = tid >> 6;
    const int wm   = wid >> 2;
    const int wn   = wid & 3;

    const int ar    = lane & 15;
    const int swz   = ((lane >> 4) ^ ((ar >> 1) & 3)) << 4;
    const int aoffb = ar * 64 + swz;
    const int boffb = (wn * 16 + ar) * 64 + swz;

    f32x4 acc[4][8];
    #pragma unroll
    for (int g = 0; g < 4; ++g)
        #pragma unroll
        for (int m = 0; m < 8; ++m)
            acc[g][m] = (f32x4){0.f, 0.f, 0.f, 0.f};

    bf16x8 aFr[8], bFr[4];

    #pragma unroll 1
    for (int j = 0; j < 32; ++j) {
        const int buf = (j & 3) << 15;
        BAR();
        #pragma unroll
        for (int mh = 0; mh < 2; ++mh)
            #pragma unroll
            for (int mi = 0; mi < 4; ++mi)
                DSR(aFr[mh * 4 + mi],
                    buf + wm * 8192 + mh * 4096 + mi * 1024 + aoffb);
        #pragma unroll
        for (int g = 0; g < 4; ++g)
            DSR(bFr[g], buf + 16384 + g * 4096 + boffb);
        LGK0();
        __builtin_amdgcn_s_setprio(1);
        #pragma unroll
        for (int g = 0; g < 4; ++g)
            #pragma unroll
            for (int m = 0; m < 8; ++m)
                acc[g][m] = __builtin_amdgcn_mfma_f32_16x16x32_bf16(
                    aFr[m], bFr[g], acc[g][m], 0, 0, 0);
        __builtin_amdgcn_s_setprio(0);
    }

    float s = 0.f;
    #pragma unroll
    for (int g = 0; g < 4; ++g)
        #pragma unroll
        for (int m = 0; m < 8; ++m)
            s += acc[g][m][0] + acc[g][m][1] + acc[g][m][2] + acc[g][m][3];
    out[(size_t)blockIdx.x * 512 + tid] = s;
}

extern "C" void kernel_launch(void* const* d_in, const int* in_sizes, int n_in,
                              void* d_out, int out_size, void* d_ws, size_t ws_size,
                              hipStream_t stream) {
    const float* x   = (const float*)d_in[0];
    const float* h   = (const float*)d_in[1];
    const float* c   = (const float*)d_in[2];
    const float* W_i = (const float*)d_in[3];
    const float* b_i = (const float*)d_in[4];
    const float* W_f = (const float*)d_in[5];
    const float* b_f = (const float*)d_in[6];
    const float* W_o = (const float*)d_in[7];
    const float* b_o = (const float*)d_in[8];
    const float* W_c = (const float*)d_in[9];
    const float* b_c = (const float*)d_in[10];

    unsigned short* Apre = (unsigned short*)d_ws;
    unsigned short* Bpre = (unsigned short*)((char*)d_ws + 33554432);

    float* h_out = (float*)d_out;
    float* c_out = h_out + (size_t)16384 * 512;

    (void)hipFuncSetAttribute(reinterpret_cast<const void*>(lstm_gemm8),
                              hipFuncAttributeMaxDynamicSharedMemorySize, 131072);
    (void)hipFuncSetAttribute(reinterpret_cast<const void*>(probe_nostage),
                              hipFuncAttributeMaxDynamicSharedMemorySize, 131072);

    conv_a_kernel<<<8192, 256, 0, stream>>>(x, h, Apre);
    conv_w_kernel<<<1024, 256, 0, stream>>>(W_i, W_f, W_o, W_c, Bpre);
    lstm_gemm8<<<512, 512, 131072, stream>>>((const char*)Apre, (const char*)Bpre,
                                             c, b_i, b_f, b_o, b_c, h_out, c_out);
    // diagnostic probe: writes junk into d_ws (Apre region), which the
    // prepasses fully rewrite at the start of every replay -> deterministic.
    probe_nostage<<<512, 512, 131072, stream>>>((float*)d_ws);
}

// Round 7
// 120.396 us; speedup vs baseline: 1.2630x; 1.2630x over previous
//
#include <hip/hip_runtime.h>
#include <hip/hip_bf16.h>
#include <cstdint>

// LSTM cell, B=16384, IN=512, H=512, fused 4-gate bf16 MFMA GEMM.
// Round 7: occupancy 2x. Block 256x128 (4wm x 2wn waves), acc 64 VGPR/thread,
// 3-deep 24KB ring (72KB LDS) -> 2 blocks/CU, 16 waves/CU via
// __launch_bounds__(512,4). Ring-3/lead-2, counted vmcnt(3).

typedef __attribute__((ext_vector_type(8))) __bf16 bf16x8;
typedef __attribute__((ext_vector_type(4))) float f32x4;
typedef __attribute__((address_space(3))) char lds_char;

#define GLOAD_LDS16(gp, lp)                                                        \
    __builtin_amdgcn_global_load_lds(                                              \
        (const __attribute__((address_space(1))) void*)(gp),                       \
        (__attribute__((address_space(3))) void*)(lp), 16, 0, 0)

#define BAR()  asm volatile("s_barrier" ::: "memory")
#define VMW3() asm volatile("s_waitcnt vmcnt(3)" ::: "memory")
#define VMW0() asm volatile("s_waitcnt vmcnt(0)" ::: "memory")
#define LGK0() { asm volatile("s_waitcnt lgkmcnt(0)" ::: "memory");                \
                 __builtin_amdgcn_sched_barrier(0); }
#define DSR(dst, off)                                                              \
    asm volatile("ds_read_b128 %0, %1" : "=v"(dst) : "v"(lds3 + (off)))

__device__ __forceinline__ unsigned short f2bf(float f) {
    unsigned int u = __float_as_uint(f);
    u = (u + 0x7FFFu + ((u >> 16) & 1u)) >> 16;   // RNE
    return (unsigned short)u;
}
__device__ __forceinline__ float tanh_fast(float x) {
    float ax = fabsf(x);
    float e  = __expf(2.f * ax);
    float t  = 1.f - 2.f / (e + 1.f);
    return copysignf(t, x);
}

// ---------------- prepass A (unchanged, verified) ----------------
// A_pre: [mt=64][t=32] 16KB slices, slice t covers k[t*32, t*32+32).
// chunk p: row = p>>2 (256 rows), kc = (p&3) ^ ((row>>1)&3).
__global__ __launch_bounds__(256) void conv_a_kernel(const float* __restrict__ x,
                                                     const float* __restrict__ h,
                                                     unsigned short* __restrict__ A) {
    int G  = blockIdx.x * 256 + threadIdx.x;
    int b  = G >> 10;
    int p  = G & 1023;
    int mt = b >> 5;
    int kt = (b >> 1) & 15;
    int ks = b & 1;
    int row = p >> 2;
    int c   = (p & 3) ^ ((row >> 1) & 3);
    int r   = mt * 256 + row;
    int k0  = kt * 64 + ks * 32 + c * 8;
    const float* src = (k0 < 512) ? (x + (size_t)r * 512 + k0)
                                  : (h + (size_t)r * 512 + (k0 - 512));
    const float4* s4 = reinterpret_cast<const float4*>(src);
    float4 v0 = s4[0];
    float4 v1 = s4[1];
    uint4 o;
    o.x = (unsigned)f2bf(v0.x) | ((unsigned)f2bf(v0.y) << 16);
    o.y = (unsigned)f2bf(v0.z) | ((unsigned)f2bf(v0.w) << 16);
    o.z = (unsigned)f2bf(v1.x) | ((unsigned)f2bf(v1.y) << 16);
    o.w = (unsigned)f2bf(v1.z) | ((unsigned)f2bf(v1.w) << 16);
    *reinterpret_cast<uint4*>(A + ((size_t)b * 1024 + p) * 8) = o;
}

// ---------------- prepass B (re-tiled: 8KB slices, 128 n-cols) ----------------
// B_pre: [nb=16][t=32] 8KB slices. chunk p (0..511): col = p>>2 (0..127),
// kc = (p&3) ^ ((col>>1)&3); col = g*32 + h_local; n = nb*32 + h_local;
// k0 = t*32 + kc*8. value = bf16(W_g[k0+u][n]), u=0..7.
__global__ __launch_bounds__(256) void conv_w_kernel(const float* __restrict__ w0,
                                                     const float* __restrict__ w1,
                                                     const float* __restrict__ w2,
                                                     const float* __restrict__ w3,
                                                     unsigned short* __restrict__ Wt) {
    int G  = blockIdx.x * 256 + threadIdx.x;   // 262,144 chunks
    int b  = G >> 9;    // 0..511
    int p  = G & 511;
    int nb = b >> 5;    // 0..15
    int t  = b & 31;    // K-tile
    int col = p >> 2;   // 0..127
    int kc  = (p & 3) ^ ((col >> 1) & 3);
    int g   = col >> 5;
    int n   = nb * 32 + (col & 31);
    int k0  = t * 32 + kc * 8;
    const float* Wg = (g == 0) ? w0 : (g == 1) ? w1 : (g == 2) ? w2 : w3;
    unsigned short us[8];
    #pragma unroll
    for (int u = 0; u < 8; ++u) us[u] = f2bf(Wg[(size_t)(k0 + u) * 512 + n]);
    uint4 o;
    o.x = (unsigned)us[0] | ((unsigned)us[1] << 16);
    o.y = (unsigned)us[2] | ((unsigned)us[3] << 16);
    o.z = (unsigned)us[4] | ((unsigned)us[5] << 16);
    o.w = (unsigned)us[6] | ((unsigned)us[7] << 16);
    *reinterpret_cast<uint4*>(Wt + ((size_t)b * 512 + p) * 8) = o;
}

// ---------------- fused GEMM: 256x128 tile, 2 blocks/CU ----------------
// LDS ring: 3 bufs x 24KB (A 16KB + B 8KB). Ring-3, lead-2, vmcnt(3).
__global__ __launch_bounds__(512, 4) void lstm_gemm8(
    const char* __restrict__ Apre, const char* __restrict__ Bpre,
    const float* __restrict__ c_cur,
    const float* __restrict__ bi_p, const float* __restrict__ bf_p,
    const float* __restrict__ bo_p, const float* __restrict__ bc_p,
    float* __restrict__ h_out, float* __restrict__ c_out)
{
    extern __shared__ char smem[];
    lds_char* lds3 = (lds_char*)smem;
    const int tid  = threadIdx.x;
    const int lane = tid & 63;
    const int wid  = tid >> 6;    // 0..7
    const int wm   = wid >> 1;    // 0..3 (64-row group)
    const int wn   = wid & 1;     // 0..1 (16-h group)

    // 1024 blocks, bijective XCD swizzle (1024%8==0): each XCD gets 2 nb panels
    const int orig = (blockIdx.x & 7) * 128 + (blockIdx.x >> 3);
    const int nb   = orig >> 6;   // 0..15 (32-h panel)
    const int mt   = orig & 63;   // 0..63 (256-row panel)

    const int ar    = lane & 15;
    const int swz   = ((lane >> 4) ^ ((ar >> 1) & 3)) << 4;
    const int aoffb = ar * 64 + swz;
    const int boffb = 16384 + (wn * 16 + ar) * 64 + swz;
    const int swl   = wid * 1024;

    const char* ApreB = Apre + (((size_t)mt * 32) << 14) + (size_t)tid * 16;
    const char* BpreB = Bpre + (((size_t)nb * 32) << 13) + (size_t)tid * 16;

    // stage K-tile t into ring buffer at byte bb: A 16KB (2 loads) + B 8KB (1)
#define STAGE(t, bb) {                                                  \
        const char* ga_ = ApreB + (((size_t)(t)) << 14);                \
        const char* gb_ = BpreB + (((size_t)(t)) << 13);                \
        GLOAD_LDS16(ga_,        smem + (bb) + swl);                     \
        GLOAD_LDS16(ga_ + 8192, smem + (bb) + 8192 + swl);              \
        GLOAD_LDS16(gb_,        smem + (bb) + 16384 + swl); }

    f32x4 acc[4][4];   // [gate][m-frag] = 64 VGPR
    #pragma unroll
    for (int g = 0; g < 4; ++g)
        #pragma unroll
        for (int m = 0; m < 4; ++m)
            acc[g][m] = (f32x4){0.f, 0.f, 0.f, 0.f};

    bf16x8 aFr[4], bFr[4];

    // prologue: stage K-tiles 0,1 into bufs 0,1 (6 loads in flight)
    STAGE(0, 0);
    STAGE(1, 24576);

    #pragma unroll 1
    for (int j = 0; j < 32; ++j) {
        // ring position: buf(j) cycles 0,24576,49152
        const int buf  = (j % 3) * 24576;
        const int bufN = ((j + 2) % 3) * 24576;

        if (j < 31) { VMW3(); } else { VMW0(); }
        BAR();
        // stage j+2 into buf((j+2)%3) == buf(j-1): safe, all reads of j-1
        // retired before this barrier (lgkmcnt(0) preceded it in iter j-1).
        if (j < 30) STAGE(j + 2, bufN);

        // A frags: rows wm*64 + mi*16 + ar; k-chunk lane>>4 (XOR-swizzled)
        #pragma unroll
        for (int mi = 0; mi < 4; ++mi)
            DSR(aFr[mi], buf + wm * 4096 + mi * 1024 + aoffb);
        // B frags: col g*32 + wn*16 + ar
        #pragma unroll
        for (int g = 0; g < 4; ++g)
            DSR(bFr[g], buf + g * 2048 + boffb);

        LGK0();
        __builtin_amdgcn_s_setprio(1);
        #pragma unroll
        for (int g = 0; g < 4; ++g)
            #pragma unroll
            for (int m = 0; m < 4; ++m)
                acc[g][m] = __builtin_amdgcn_mfma_f32_16x16x32_bf16(
                    aFr[m], bFr[g], acc[g][m], 0, 0, 0);
        __builtin_amdgcn_s_setprio(0);
    }

    // fused LSTM epilogue: all 4 gates in-lane
    const int r4   = (lane >> 4) * 4;
    const int hcol = nb * 32 + wn * 16 + ar;
    const float bii = bi_p[hcol], bff = bf_p[hcol];
    const float boo = bo_p[hcol], bcc = bc_p[hcol];
    #pragma unroll
    for (int m = 0; m < 4; ++m) {
        const int rowb = mt * 256 + wm * 64 + m * 16 + r4;
        #pragma unroll
        for (int rr = 0; rr < 4; ++rr) {
            const size_t o = (size_t)(rowb + rr) * 512 + hcol;
            float gi = acc[0][m][rr] + bii;
            float gf = acc[1][m][rr] + bff;
            float go = acc[2][m][rr] + boo;
            float gc = acc[3][m][rr] + bcc;
            float is = 1.f / (1.f + __expf(-gi));
            float fs = 1.f / (1.f + __expf(-gf));
            float os = 1.f / (1.f + __expf(-go));
            float ct = tanh_fast(gc);
            float cn = fs * c_cur[o] + is * ct;
            h_out[o] = os * tanh_fast(cn);
            c_out[o] = cn;
        }
    }
#undef STAGE
}

extern "C" void kernel_launch(void* const* d_in, const int* in_sizes, int n_in,
                              void* d_out, int out_size, void* d_ws, size_t ws_size,
                              hipStream_t stream) {
    const float* x   = (const float*)d_in[0];
    const float* h   = (const float*)d_in[1];
    const float* c   = (const float*)d_in[2];
    const float* W_i = (const float*)d_in[3];
    const float* b_i = (const float*)d_in[4];
    const float* W_f = (const float*)d_in[5];
    const float* b_f = (const float*)d_in[6];
    const float* W_o = (const float*)d_in[7];
    const float* b_o = (const float*)d_in[8];
    const float* W_c = (const float*)d_in[9];
    const float* b_c = (const float*)d_in[10];

    unsigned short* Apre = (unsigned short*)d_ws;                      // 33,554,432 B
    unsigned short* Bpre = (unsigned short*)((char*)d_ws + 33554432);  //  4,194,304 B

    float* h_out = (float*)d_out;
    float* c_out = h_out + (size_t)16384 * 512;

    (void)hipFuncSetAttribute(reinterpret_cast<const void*>(lstm_gemm8),
                              hipFuncAttributeMaxDynamicSharedMemorySize, 73728);

    conv_a_kernel<<<8192, 256, 0, stream>>>(x, h, Apre);
    conv_w_kernel<<<1024, 256, 0, stream>>>(W_i, W_f, W_o, W_c, Bpre);
    lstm_gemm8<<<1024, 512, 73728, stream>>>((const char*)Apre, (const char*)Bpre,
                                             c, b_i, b_f, b_o, b_c, h_out, c_out);
}

// Round 8
// 108.996 us; speedup vs baseline: 1.3951x; 1.1046x over previous
//
#include <hip/hip_runtime.h>
#include <hip/hip_bf16.h>
#include <cstdint>

// LSTM cell, B=16384, IN=512, H=512, fused 4-gate bf16 MFMA GEMM.
// Round 8: r5 structure (256x256 tile, ring-4/lead-3, counted vmcnt(8))
// + counted-lgkmcnt batched read/MFMA interleave (4 batches of 3 ds_reads,
// MFMA groups 2/6/10/14 behind lgkmcnt(9/6/3/0)) so LDS reads overlap MFMA.

typedef __attribute__((ext_vector_type(8))) __bf16 bf16x8;
typedef __attribute__((ext_vector_type(4))) float f32x4;
typedef __attribute__((address_space(3))) char lds_char;

#define GLOAD_LDS16(gp, lp)                                                        \
    __builtin_amdgcn_global_load_lds(                                              \
        (const __attribute__((address_space(1))) void*)(gp),                       \
        (__attribute__((address_space(3))) void*)(lp), 16, 0, 0)

#define BAR()  asm volatile("s_barrier" ::: "memory")
#define VMW8() asm volatile("s_waitcnt vmcnt(8)" ::: "memory")
#define VMW4() asm volatile("s_waitcnt vmcnt(4)" ::: "memory")
#define VMW0() asm volatile("s_waitcnt vmcnt(0)" ::: "memory")
#define LGK(n) { asm volatile("s_waitcnt lgkmcnt(" #n ")" ::: "memory");           \
                 __builtin_amdgcn_sched_barrier(0); }
#define DSR(dst, off)                                                              \
    asm volatile("ds_read_b128 %0, %1" : "=v"(dst) : "v"(lds3 + (off)))

__device__ __forceinline__ unsigned short f2bf(float f) {
    unsigned int u = __float_as_uint(f);
    u = (u + 0x7FFFu + ((u >> 16) & 1u)) >> 16;   // RNE
    return (unsigned short)u;
}
__device__ __forceinline__ float tanh_fast(float x) {
    float ax = fabsf(x);
    float e  = __expf(2.f * ax);
    float t  = 1.f - 2.f / (e + 1.f);
    return copysignf(t, x);
}

// ---------------- prepass A (r5, verified) ----------------
__global__ __launch_bounds__(256) void conv_a_kernel(const float* __restrict__ x,
                                                     const float* __restrict__ h,
                                                     unsigned short* __restrict__ A) {
    int G  = blockIdx.x * 256 + threadIdx.x;
    int b  = G >> 10;
    int p  = G & 1023;
    int mt = b >> 5;
    int kt = (b >> 1) & 15;
    int ks = b & 1;
    int row = p >> 2;
    int c   = (p & 3) ^ ((row >> 1) & 3);
    int r   = mt * 256 + row;
    int k0  = kt * 64 + ks * 32 + c * 8;
    const float* src = (k0 < 512) ? (x + (size_t)r * 512 + k0)
                                  : (h + (size_t)r * 512 + (k0 - 512));
    const float4* s4 = reinterpret_cast<const float4*>(src);
    float4 v0 = s4[0];
    float4 v1 = s4[1];
    uint4 o;
    o.x = (unsigned)f2bf(v0.x) | ((unsigned)f2bf(v0.y) << 16);
    o.y = (unsigned)f2bf(v0.z) | ((unsigned)f2bf(v0.w) << 16);
    o.z = (unsigned)f2bf(v1.x) | ((unsigned)f2bf(v1.y) << 16);
    o.w = (unsigned)f2bf(v1.z) | ((unsigned)f2bf(v1.w) << 16);
    *reinterpret_cast<uint4*>(A + ((size_t)b * 1024 + p) * 8) = o;
}

// ---------------- prepass B (r5, verified) ----------------
__global__ __launch_bounds__(256) void conv_w_kernel(const float* __restrict__ w0,
                                                     const float* __restrict__ w1,
                                                     const float* __restrict__ w2,
                                                     const float* __restrict__ w3,
                                                     unsigned short* __restrict__ Wt) {
    int G  = blockIdx.x * 256 + threadIdx.x;
    int b  = G >> 10;
    int p  = G & 1023;
    int nb = b >> 5;
    int kt = (b >> 1) & 15;
    int ks = b & 1;
    int col = p >> 2;
    int c   = (p & 3) ^ ((col >> 1) & 3);
    int g   = col >> 6;
    int hh  = col & 63;
    int n   = nb * 64 + hh;
    int k0  = kt * 64 + ks * 32 + c * 8;
    const float* Wg = (g == 0) ? w0 : (g == 1) ? w1 : (g == 2) ? w2 : w3;
    unsigned short us[8];
    #pragma unroll
    for (int u = 0; u < 8; ++u) us[u] = f2bf(Wg[(size_t)(k0 + u) * 512 + n]);
    uint4 o;
    o.x = (unsigned)us[0] | ((unsigned)us[1] << 16);
    o.y = (unsigned)us[2] | ((unsigned)us[3] << 16);
    o.z = (unsigned)us[4] | ((unsigned)us[5] << 16);
    o.w = (unsigned)us[6] | ((unsigned)us[7] << 16);
    *reinterpret_cast<uint4*>(Wt + ((size_t)b * 1024 + p) * 8) = o;
}

// ---------------- fused GEMM: ring-4, batched lgkm interleave ----------------
__global__ __launch_bounds__(512, 2) void lstm_gemm8(
    const char* __restrict__ Apre, const char* __restrict__ Bpre,
    const float* __restrict__ c_cur,
    const float* __restrict__ bi_p, const float* __restrict__ bf_p,
    const float* __restrict__ bo_p, const float* __restrict__ bc_p,
    float* __restrict__ h_out, float* __restrict__ c_out)
{
    extern __shared__ char smem[];
    lds_char* lds3 = (lds_char*)smem;
    const int tid  = threadIdx.x;
    const int lane = tid & 63;
    const int wid  = tid >> 6;
    const int wm   = wid >> 2;    // 0..1
    const int wn   = wid & 3;     // 0..3

    const int nb = blockIdx.x & 7;
    const int mt = blockIdx.x >> 3;

    const int ar    = lane & 15;
    const int swz   = ((lane >> 4) ^ ((ar >> 1) & 3)) << 4;
    const int aoffb = ar * 64 + swz;
    const int boffb = (wn * 16 + ar) * 64 + swz;
    const int swl   = wid * 1024;

    const char* ApreB = Apre + (((size_t)mt * 32) << 14) + (size_t)tid * 16;
    const char* BpreB = Bpre + (((size_t)nb * 32) << 14) + (size_t)tid * 16;

#define STAGE(t, bb) {                                                  \
        const char* ga_ = ApreB + (((size_t)(t)) << 14);                \
        const char* gb_ = BpreB + (((size_t)(t)) << 14);                \
        GLOAD_LDS16(ga_,        smem + (bb) + swl);                     \
        GLOAD_LDS16(ga_ + 8192, smem + (bb) + 8192 + swl);              \
        GLOAD_LDS16(gb_,        smem + (bb) + 16384 + swl);             \
        GLOAD_LDS16(gb_ + 8192, smem + (bb) + 16384 + 8192 + swl); }

    f32x4 acc[4][8];
    #pragma unroll
    for (int g = 0; g < 4; ++g)
        #pragma unroll
        for (int m = 0; m < 8; ++m)
            acc[g][m] = (f32x4){0.f, 0.f, 0.f, 0.f};

    bf16x8 aFr[8], bFr[4];

#define MM1(m, g) acc[g][m] = __builtin_amdgcn_mfma_f32_16x16x32_bf16(   \
                      aFr[m], bFr[g], acc[g][m], 0, 0, 0);

    // prologue: stage K-tiles 0,1,2 into ring bufs 0,1,2 (12 loads in flight)
    STAGE(0, 0);
    STAGE(1, 32768);
    STAGE(2, 65536);

    #pragma unroll 1
    for (int j = 0; j < 32; ++j) {
        const int buf  = (j & 3) << 15;
        const int bufN = ((j + 3) & 3) << 15;

        if (j < 30)      { VMW8(); }
        else if (j == 30){ VMW4(); }
        else             { VMW0(); }
        BAR();
        if (j < 29) STAGE(j + 3, bufN);

        const int ab = buf + wm * 8192 + aoffb;
        const int bb = buf + 16384 + boffb;
        // batch 0: B0,B1,A0
        DSR(bFr[0], bb);
        DSR(bFr[1], bb + 4096);
        DSR(aFr[0], ab);
        // batch 1: A1,A2,A3
        DSR(aFr[1], ab + 1024);
        DSR(aFr[2], ab + 2048);
        DSR(aFr[3], ab + 3072);
        // batch 2: B2,B3,A4
        DSR(bFr[2], bb + 8192);
        DSR(bFr[3], bb + 12288);
        DSR(aFr[4], ab + 4096);
        // batch 3: A5,A6,A7
        DSR(aFr[5], ab + 5120);
        DSR(aFr[6], ab + 6144);
        DSR(aFr[7], ab + 7168);

        __builtin_amdgcn_s_setprio(1);
        LGK(9);   // batch 0 done
        MM1(0, 0) MM1(0, 1)
        LGK(6);   // batch 1 done
        MM1(1, 0) MM1(1, 1) MM1(2, 0) MM1(2, 1) MM1(3, 0) MM1(3, 1)
        LGK(3);   // batch 2 done
        MM1(4, 0) MM1(4, 1)
        MM1(0, 2) MM1(0, 3) MM1(1, 2) MM1(1, 3)
        MM1(2, 2) MM1(2, 3) MM1(3, 2) MM1(3, 3)
        LGK(0);   // batch 3 done
        MM1(4, 2) MM1(4, 3)
        MM1(5, 0) MM1(5, 1) MM1(5, 2) MM1(5, 3)
        MM1(6, 0) MM1(6, 1) MM1(6, 2) MM1(6, 3)
        MM1(7, 0) MM1(7, 1) MM1(7, 2) MM1(7, 3)
        __builtin_amdgcn_s_setprio(0);
    }

    // fused LSTM epilogue: all 4 gates in-lane
    const int r4   = (lane >> 4) * 4;
    const int hcol = nb * 64 + wn * 16 + ar;
    const float bii = bi_p[hcol], bff = bf_p[hcol];
    const float boo = bo_p[hcol], bcc = bc_p[hcol];
    #pragma unroll
    for (int m = 0; m < 8; ++m) {
        const int rowb = mt * 256 + wm * 128 + m * 16 + r4;
        #pragma unroll
        for (int rr = 0; rr < 4; ++rr) {
            const size_t o = (size_t)(rowb + rr) * 512 + hcol;
            float gi = acc[0][m][rr] + bii;
            float gf = acc[1][m][rr] + bff;
            float go = acc[2][m][rr] + boo;
            float gc = acc[3][m][rr] + bcc;
            float is = 1.f / (1.f + __expf(-gi));
            float fs = 1.f / (1.f + __expf(-gf));
            float os = 1.f / (1.f + __expf(-go));
            float ct = tanh_fast(gc);
            float cn = fs * c_cur[o] + is * ct;
            h_out[o] = os * tanh_fast(cn);
            c_out[o] = cn;
        }
    }
#undef STAGE
#undef MM1
}

extern "C" void kernel_launch(void* const* d_in, const int* in_sizes, int n_in,
                              void* d_out, int out_size, void* d_ws, size_t ws_size,
                              hipStream_t stream) {
    const float* x   = (const float*)d_in[0];
    const float* h   = (const float*)d_in[1];
    const float* c   = (const float*)d_in[2];
    const float* W_i = (const float*)d_in[3];
    const float* b_i = (const float*)d_in[4];
    const float* W_f = (const float*)d_in[5];
    const float* b_f = (const float*)d_in[6];
    const float* W_o = (const float*)d_in[7];
    const float* b_o = (const float*)d_in[8];
    const float* W_c = (const float*)d_in[9];
    const float* b_c = (const float*)d_in[10];

    unsigned short* Apre = (unsigned short*)d_ws;
    unsigned short* Bpre = (unsigned short*)((char*)d_ws + 33554432);

    float* h_out = (float*)d_out;
    float* c_out = h_out + (size_t)16384 * 512;

    (void)hipFuncSetAttribute(reinterpret_cast<const void*>(lstm_gemm8),
                              hipFuncAttributeMaxDynamicSharedMemorySize, 131072);

    conv_a_kernel<<<8192, 256, 0, stream>>>(x, h, Apre);
    conv_w_kernel<<<1024, 256, 0, stream>>>(W_i, W_f, W_o, W_c, Bpre);
    lstm_gemm8<<<512, 512, 131072, stream>>>((const char*)Apre, (const char*)Bpre,
                                             c, b_i, b_f, b_o, b_c, h_out, c_out);
}